// Round 1
// baseline (367.358 us; speedup 1.0000x reference)
//
#include <hip/hip_runtime.h>
#include <math.h>

#define B_ 64
#define L_ 1024
#define D_ 64
#define TQ 64
#define TK 64
#define NQT 16
#define NTRI 136           // 16*17/2 lower-triangle tiles
#define NEGBIG (-2.0e9f)   // matches ref: NEG + NEG at masked positions

typedef float4 f4;

// ---------------------------------------------------------------------------
// K1: scores S[b,q,k] = (q.k + q.Er[k-q+1023]) / 8 for k<=q, -2e9 for k>q
// (only lower-triangle 64x64 tiles; upper tiles never written, never read)
// ---------------------------------------------------------------------------
__global__ __launch_bounds__(256) void k1_scores(
    const float* __restrict__ Q, const float* __restrict__ Kp,
    const float* __restrict__ Er, float* __restrict__ S)
{
    __shared__ f4 sQ4[D_][17];   // sQ[d][qi]  (transposed, pad 68 floats/row)
    __shared__ f4 sK4[D_][17];   // sK[d][ki]
    __shared__ f4 sE4[D_][33];   // sE[d][t], t = (k-q+1023) - l_base, width 128

    const int tid = threadIdx.x;
    const int bid = blockIdx.x;
    const int b = bid / NTRI;
    const int t = bid - b * NTRI;
    // triangle decode: qt = row, kt = col (kt <= qt)
    int qt = (int)((sqrtf((float)(8 * t + 1)) - 1.0f) * 0.5f);
    while ((qt + 1) * (qt + 2) / 2 <= t) ++qt;
    while (qt * (qt + 1) / 2 > t) --qt;
    const int kt = t - qt * (qt + 1) / 2;
    const int q0 = qt * TQ, k0 = kt * TK;

    const int c4 = tid & 15;     // float4 column within a 64-float row
    const int rsub = tid >> 4;   // 0..15

    float* sQf = (float*)sQ4;
    float* sKf = (float*)sK4;
    float* sEf = (float*)sE4;

    // stage Q,K tiles transposed: s*[d][row]
#pragma unroll
    for (int i = 0; i < 4; ++i) {
        int row = rsub + 16 * i;  // 0..63
        f4 qv = *(const f4*)(Q + ((size_t)b * L_ + q0 + row) * D_ + 4 * c4);
        f4 kv = *(const f4*)(Kp + ((size_t)b * L_ + k0 + row) * D_ + 4 * c4);
        sQf[(4 * c4 + 0) * 68 + row] = qv.x; sQf[(4 * c4 + 1) * 68 + row] = qv.y;
        sQf[(4 * c4 + 2) * 68 + row] = qv.z; sQf[(4 * c4 + 3) * 68 + row] = qv.w;
        sKf[(4 * c4 + 0) * 68 + row] = kv.x; sKf[(4 * c4 + 1) * 68 + row] = kv.y;
        sKf[(4 * c4 + 2) * 68 + row] = kv.z; sKf[(4 * c4 + 3) * 68 + row] = kv.w;
    }
    // stage Er window: l = l_base + t, t in [0,128); clamp OOB (masked pairs only)
    const int l_base = k0 - q0 + (L_ - TQ);  // k0 - q0 + 960, >= 0 for kt<=qt
#pragma unroll
    for (int i = 0; i < 8; ++i) {
        int trow = rsub + 16 * i;  // 0..127
        int l = l_base + trow;
        l = l < 0 ? 0 : (l > L_ - 1 ? L_ - 1 : l);
        f4 ev = *(const f4*)(Er + (size_t)l * D_ + 4 * c4);
        sEf[(4 * c4 + 0) * 132 + trow] = ev.x; sEf[(4 * c4 + 1) * 132 + trow] = ev.y;
        sEf[(4 * c4 + 2) * 132 + trow] = ev.z; sEf[(4 * c4 + 3) * 132 + trow] = ev.w;
    }
    __syncthreads();

    // per-thread 4q x 4k block
    const int qsel = tid >> 4;            // qi0 = 4*qsel
    const int ksel = tid & 15;            // kj0 = 4*ksel
    const int e4 = ksel - qsel + 15;      // (kj0 - qi0 + 60)/4, in [0,30]

    float acc[4][4] = {};
#pragma unroll 4
    for (int j = 0; j < D_; ++j) {
        f4 qv = sQ4[j][qsel];
        f4 kv = sK4[j][ksel];
        f4 e0 = sE4[j][e4];
        f4 e1 = sE4[j][e4 + 1];
        float qa[4] = {qv.x, qv.y, qv.z, qv.w};
        float ka[4] = {kv.x, kv.y, kv.z, kv.w};
        float ea[8] = {e0.x, e0.y, e0.z, e0.w, e1.x, e1.y, e1.z, e1.w};
#pragma unroll
        for (int dq = 0; dq < 4; ++dq)
#pragma unroll
            for (int dk = 0; dk < 4; ++dk)
                acc[dq][dk] = fmaf(qa[dq], ka[dk] + ea[3 + dk - dq], acc[dq][dk]);
    }

    const int qi0 = 4 * qsel, kj0 = 4 * ksel;
    float* Sbase = S + ((size_t)b * L_ + q0) * L_ + k0;
#pragma unroll
    for (int dq = 0; dq < 4; ++dq) {
        int gq = q0 + qi0 + dq;
        int gk = k0 + kj0;
        f4 o;
        o.x = (gk + 0 > gq) ? NEGBIG : acc[dq][0] * 0.125f;
        o.y = (gk + 1 > gq) ? NEGBIG : acc[dq][1] * 0.125f;
        o.z = (gk + 2 > gq) ? NEGBIG : acc[dq][2] * 0.125f;
        o.w = (gk + 3 > gq) ? NEGBIG : acc[dq][3] * 0.125f;
        *(f4*)(Sbase + (size_t)(qi0 + dq) * L_ + kj0) = o;
    }
}

// ---------------------------------------------------------------------------
// K2: row softmax in place. One wave per row; reads only k <= ceil4(q+1),
// writes probs there and exact zeros for the rest of the row.
// ---------------------------------------------------------------------------
__global__ __launch_bounds__(256) void k2_softmax(float* __restrict__ S)
{
    const int w = threadIdx.x >> 6, lane = threadIdx.x & 63;
    const size_t r = (size_t)blockIdx.x * 4 + w;
    const int q = (int)(r & (L_ - 1));
    float* row = S + r * L_;
    const int nact = (q + 4) >> 2;  // active float4 count (<= written coverage)

    f4 x[4];
    float m = -3.0e38f;
#pragma unroll
    for (int i = 0; i < 4; ++i) {
        int c = lane + 64 * i;
        if (c < nact) {
            x[i] = *(const f4*)(row + 4 * c);
            m = fmaxf(m, fmaxf(fmaxf(x[i].x, x[i].y), fmaxf(x[i].z, x[i].w)));
        }
    }
#pragma unroll
    for (int o = 32; o >= 1; o >>= 1) m = fmaxf(m, __shfl_xor(m, o, 64));

    float s = 0.0f;
#pragma unroll
    for (int i = 0; i < 4; ++i) {
        int c = lane + 64 * i;
        if (c < nact) {
            x[i].x = __expf(x[i].x - m); x[i].y = __expf(x[i].y - m);
            x[i].z = __expf(x[i].z - m); x[i].w = __expf(x[i].w - m);
            s += (x[i].x + x[i].y) + (x[i].z + x[i].w);
        }
    }
#pragma unroll
    for (int o = 32; o >= 1; o >>= 1) s += __shfl_xor(s, o, 64);
    const float inv = 1.0f / s;

#pragma unroll
    for (int i = 0; i < 4; ++i) {
        int c = lane + 64 * i;
        f4 y;
        if (c < nact) {
            y.x = x[i].x * inv; y.y = x[i].y * inv;
            y.z = x[i].z * inv; y.w = x[i].w * inv;
        } else {
            y.x = 0.0f; y.y = 0.0f; y.z = 0.0f; y.w = 0.0f;
        }
        *(f4*)(row + 4 * c) = y;
    }
}

// ---------------------------------------------------------------------------
// K3: O[b, q-tile, :] = P[b, q-tile, :] @ V[b]  (causal k-tiles only;
// P is exactly 0 above the diagonal so the diagonal tile is safe)
// ---------------------------------------------------------------------------
__global__ __launch_bounds__(256) void k3_pv(
    const float* __restrict__ P, const float* __restrict__ V,
    float* __restrict__ O)
{
    __shared__ f4 sP4[TK][17];   // transposed: sP[k][q]
    __shared__ f4 sV4[TK][17];   // natural:    sV[k][d]

    const int tid = threadIdx.x;
    const int qt = blockIdx.x, b = blockIdx.y;
    const int q0 = qt * TQ;
    const int c4 = tid & 15, rsub = tid >> 4;
    const int qsel = tid >> 4, dsel = tid & 15;

    float* sPf = (float*)sP4;
    float acc[4][4] = {};

    for (int kt = 0; kt <= qt; ++kt) {
        const int k0 = kt * TK;
        __syncthreads();
#pragma unroll
        for (int i = 0; i < 4; ++i) {
            int row = rsub + 16 * i;
            f4 pv = *(const f4*)(P + ((size_t)b * L_ + q0 + row) * L_ + k0 + 4 * c4);
            sPf[(4 * c4 + 0) * 68 + row] = pv.x; sPf[(4 * c4 + 1) * 68 + row] = pv.y;
            sPf[(4 * c4 + 2) * 68 + row] = pv.z; sPf[(4 * c4 + 3) * 68 + row] = pv.w;
            sV4[row][c4] = *(const f4*)(V + ((size_t)b * L_ + k0 + row) * D_ + 4 * c4);
        }
        __syncthreads();
#pragma unroll 8
        for (int kk = 0; kk < TK; ++kk) {
            f4 p4 = sP4[kk][qsel];
            f4 v4 = sV4[kk][dsel];
            float pa[4] = {p4.x, p4.y, p4.z, p4.w};
            float va[4] = {v4.x, v4.y, v4.z, v4.w};
#pragma unroll
            for (int dq = 0; dq < 4; ++dq)
#pragma unroll
                for (int dv = 0; dv < 4; ++dv)
                    acc[dq][dv] = fmaf(pa[dq], va[dv], acc[dq][dv]);
        }
    }

#pragma unroll
    for (int dq = 0; dq < 4; ++dq) {
        f4 o;
        o.x = acc[dq][0]; o.y = acc[dq][1]; o.z = acc[dq][2]; o.w = acc[dq][3];
        *(f4*)(O + ((size_t)b * L_ + q0 + 4 * qsel + dq) * D_ + 4 * dsel) = o;
    }
}

// ---------------------------------------------------------------------------
extern "C" void kernel_launch(void* const* d_in, const int* in_sizes, int n_in,
                              void* d_out, int out_size, void* d_ws, size_t ws_size,
                              hipStream_t stream)
{
    const float* Q  = (const float*)d_in[0];
    const float* K  = (const float*)d_in[1];
    const float* V  = (const float*)d_in[2];
    const float* Er = (const float*)d_in[3];
    // d_in[4] is the causal mask; it is deterministic (triu) so we compute it.

    float* Out  = (float*)d_out;                          // [B, L, D]
    float* Attn = (float*)d_out + (size_t)B_ * L_ * D_;   // [B, L, L] (also scratch)

    k1_scores<<<B_ * NTRI, 256, 0, stream>>>(Q, K, Er, Attn);
    k2_softmax<<<B_ * L_ / 4, 256, 0, stream>>>(Attn);
    k3_pv<<<dim3(NQT, B_), 256, 0, stream>>>(Attn, V, Out);
}

// Round 2
// 194.492 us; speedup vs baseline: 1.8888x; 1.8888x over previous
//
#include <hip/hip_runtime.h>
#include <math.h>

#define B_ 64
#define L_ 1024
#define D_ 64
#define NQT 16
#define NTRI 136           // 16*17/2 lower-triangle tiles
#define NEGBIG (-2.0e9f)   // matches ref: NEG + NEG at masked positions

typedef float4 f4;
typedef __attribute__((ext_vector_type(8))) short bf16x8;
typedef __attribute__((ext_vector_type(4))) float f32x4;

#define MFMA16(a, b, c) __builtin_amdgcn_mfma_f32_16x16x32_bf16(a, b, c, 0, 0, 0)

// round-to-nearest-even f32 -> bf16 (no NaN inputs here)
__device__ __forceinline__ ushort f2bf(float x) {
    unsigned u = __float_as_uint(x);
    return (ushort)((u + 0x7FFFu + ((u >> 16) & 1u)) >> 16);
}

// XOR swizzle for stride-128B rows: spreads both 16-consecutive-row fragment
// reads and 4-strided transpose writes across 8 16B slots (<=2-way conflicts)
#define SWZ(row, off) ((off) ^ ((((row) ^ ((row) >> 3)) & 7) << 4))

// ---------------------------------------------------------------------------
// K1: S[b,q,k] = (q.k + q.Er[k-q+1023]) / 8 for k<=q, NEGBIG above diagonal.
// bf16 MFMA: content = Q @ K^T (64x64), rel = Q @ E_win^T (64x128) + skew
// gather through LDS. Only lower-triangle tiles launched.
// ---------------------------------------------------------------------------
__global__ __launch_bounds__(256) void k1_scores(
    const float* __restrict__ Q, const float* __restrict__ Kp,
    const float* __restrict__ Er, float* __restrict__ S)
{
    __shared__ __align__(16) char lds[36864];
    ushort* sQ = (ushort*)lds;        // [64][72] bf16
    ushort* sK = sQ + 64 * 72;        // [64][72]
    ushort* sE = sK + 64 * 72;        // [128][72]
    float*  sR = (float*)lds;         // union: [64][132] f32 (33792 B)

    const int tid = threadIdx.x;
    const int bid = blockIdx.x;
    const int b = bid / NTRI;
    const int t = bid - b * NTRI;
    int qt = (int)((sqrtf((float)(8 * t + 1)) - 1.0f) * 0.5f);
    while ((qt + 1) * (qt + 2) / 2 <= t) ++qt;
    while (qt * (qt + 1) / 2 > t) --qt;
    const int kt = t - qt * (qt + 1) / 2;
    const int q0 = qt * 64, k0 = kt * 64;

    const int c4 = tid & 15, rsub = tid >> 4;

    // stage Q, K tiles and the Er diagonal window as bf16
#pragma unroll
    for (int i = 0; i < 4; ++i) {
        int row = rsub + 16 * i;
        f4 qv = *(const f4*)(Q + ((size_t)b * L_ + q0 + row) * D_ + 4 * c4);
        f4 kv = *(const f4*)(Kp + ((size_t)b * L_ + k0 + row) * D_ + 4 * c4);
        *(ushort4*)(sQ + row * 72 + 4 * c4) =
            make_ushort4(f2bf(qv.x), f2bf(qv.y), f2bf(qv.z), f2bf(qv.w));
        *(ushort4*)(sK + row * 72 + 4 * c4) =
            make_ushort4(f2bf(kv.x), f2bf(kv.y), f2bf(kv.z), f2bf(kv.w));
    }
    const int l_base = k0 - q0 + (L_ - 64);  // >= 0 for kt<=qt
#pragma unroll
    for (int i = 0; i < 8; ++i) {
        int trow = rsub + 16 * i;
        int l = l_base + trow;
        if (l > L_ - 1) l = L_ - 1;  // clamp: only masked entries use these
        f4 ev = *(const f4*)(Er + (size_t)l * D_ + 4 * c4);
        *(ushort4*)(sE + trow * 72 + 4 * c4) =
            make_ushort4(f2bf(ev.x), f2bf(ev.y), f2bf(ev.z), f2bf(ev.w));
    }
    __syncthreads();

    const int lane = tid & 63, w = tid >> 6;
    const int fr = lane & 15, fc = lane >> 4;

    // all fragments into registers (LDS is reused for sR afterwards)
    bf16x8 qf[4][2], kf[2], ef[2][2];
#pragma unroll
    for (int rt = 0; rt < 4; ++rt)
#pragma unroll
        for (int kc = 0; kc < 2; ++kc)
            qf[rt][kc] = *(const bf16x8*)(sQ + (rt * 16 + fr) * 72 + kc * 32 + fc * 8);
#pragma unroll
    for (int kc = 0; kc < 2; ++kc)
        kf[kc] = *(const bf16x8*)(sK + (16 * w + fr) * 72 + kc * 32 + fc * 8);
#pragma unroll
    for (int c = 0; c < 2; ++c)
#pragma unroll
        for (int kc = 0; kc < 2; ++kc)
            ef[c][kc] = *(const bf16x8*)(sE + ((2 * w + c) * 16 + fr) * 72 + kc * 32 + fc * 8);
    __syncthreads();  // all waves done reading staging before sR overwrite

    f32x4 accC[4] = {};
    f32x4 accR[4][2] = {};
#pragma unroll
    for (int rt = 0; rt < 4; ++rt)
#pragma unroll
        for (int kc = 0; kc < 2; ++kc) {
            accC[rt]    = MFMA16(qf[rt][kc], kf[kc],    accC[rt]);
            accR[rt][0] = MFMA16(qf[rt][kc], ef[0][kc], accR[rt][0]);
            accR[rt][1] = MFMA16(qf[rt][kc], ef[1][kc], accR[rt][1]);
        }

    // scatter rel accumulator R[qi][t] to LDS for the skew gather
#pragma unroll
    for (int rt = 0; rt < 4; ++rt)
#pragma unroll
        for (int c = 0; c < 2; ++c)
#pragma unroll
            for (int r = 0; r < 4; ++r)
                sR[(rt * 16 + fc * 4 + r) * 132 + (2 * w + c) * 16 + fr] = accR[rt][c][r];
    __syncthreads();

    const bool diag = (qt == kt);
    float* Sbase = S + ((size_t)b * L_ + q0) * L_ + k0;
#pragma unroll
    for (int rt = 0; rt < 4; ++rt)
#pragma unroll
        for (int r = 0; r < 4; ++r) {
            int qi = rt * 16 + fc * 4 + r;
            int kj = 16 * w + fr;
            float rel = sR[qi * 132 + kj - qi + 63];   // t = kj-qi+63 in [0,126]
            float val = (accC[rt][r] + rel) * 0.125f;
            if (diag && kj > qi) val = NEGBIG;
            Sbase[(size_t)qi * L_ + kj] = val;
        }
}

// ---------------------------------------------------------------------------
// K2: per-row (max, 1/sum) stats -> stashed in O[:, 0:2] (K3 reads them before
// overwriting O). Also writes the mandatory zeros for cols >= 64*(qt+1).
// ---------------------------------------------------------------------------
__global__ __launch_bounds__(256) void k2_stats(
    const float* __restrict__ S, float* __restrict__ O)
{
    const int w = threadIdx.x >> 6, lane = threadIdx.x & 63;
    const size_t r = (size_t)blockIdx.x * 4 + w;
    const int q = (int)(r & (L_ - 1));
    const int qt = q >> 6;
    const int nT = 16 * (qt + 1);  // f4 count covered by K1's tiles
    const float* row = S + r * L_;

    float m = -3.0e38f;
    f4 x[4];
#pragma unroll
    for (int i = 0; i < 4; ++i) {
        int c = lane + 64 * i;
        if (c < nT) {
            x[i] = *(const f4*)(row + 4 * c);
            m = fmaxf(m, fmaxf(fmaxf(x[i].x, x[i].y), fmaxf(x[i].z, x[i].w)));
        }
    }
#pragma unroll
    for (int o = 32; o >= 1; o >>= 1) m = fmaxf(m, __shfl_xor(m, o, 64));

    float s = 0.0f;
#pragma unroll
    for (int i = 0; i < 4; ++i) {
        int c = lane + 64 * i;
        if (c < nT)
            s += (__expf(x[i].x - m) + __expf(x[i].y - m)) +
                 (__expf(x[i].z - m) + __expf(x[i].w - m));
    }
#pragma unroll
    for (int o = 32; o >= 1; o >>= 1) s += __shfl_xor(s, o, 64);

    // zero the never-written upper region of this row
    const f4 z = {0.0f, 0.0f, 0.0f, 0.0f};
    float* wrow = (float*)row;
#pragma unroll
    for (int i = 0; i < 4; ++i) {
        int c = nT + lane + 64 * i;
        if (c < 256) *(f4*)(wrow + 4 * c) = z;
    }
    if (lane == 0) *(float2*)(O + r * (size_t)D_) = make_float2(m, 1.0f / s);
}

// ---------------------------------------------------------------------------
// K3: per (b, q-tile): read score tiles, p = exp(s-m)/sum, write probs in
// place, stage P and V^T as bf16 in swizzled LDS, accumulate O = P @ V via
// MFMA. Epilogue overwrites the stats stash.
// ---------------------------------------------------------------------------
__global__ __launch_bounds__(256) void k3_pv(
    float* __restrict__ Sc, const float* __restrict__ V, float* __restrict__ O)
{
    __shared__ __align__(16) char sPb[64 * 128];  // P tile bf16 [64][64]
    __shared__ __align__(16) char sVb[64 * 128];  // V^T tile bf16 [d][k]

    const int tid = threadIdx.x;
    const int b = blockIdx.x;
    const int qt = 15 - (int)blockIdx.y;  // big blocks dispatch first
    const int q0 = qt * 64;
    const int c4 = tid & 15, rsub = tid >> 4;
    const int lane = tid & 63, w = tid >> 6;
    const int fr = lane & 15, fc = lane >> 4;

    float2 st_[4];
#pragma unroll
    for (int i = 0; i < 4; ++i)
        st_[i] = *(const float2*)(O + ((size_t)b * L_ + q0 + rsub + 16 * i) * D_);

    f32x4 acc[4] = {};

    for (int kt = 0; kt <= qt; ++kt) {
        const int k0 = kt * 64;
        __syncthreads();  // previous iteration's fragment reads done
        // stage P: exp/normalize, write probs to global, bf16 to LDS
#pragma unroll
        for (int i = 0; i < 4; ++i) {
            int row = rsub + 16 * i;
            float* sp = Sc + ((size_t)b * L_ + q0 + row) * L_ + k0 + 4 * c4;
            f4 s4 = *(const f4*)sp;
            float mm = st_[i].x, inv = st_[i].y;
            f4 p;
            p.x = __expf(s4.x - mm) * inv;
            p.y = __expf(s4.y - mm) * inv;
            p.z = __expf(s4.z - mm) * inv;
            p.w = __expf(s4.w - mm) * inv;
            *(f4*)sp = p;
            *(ushort4*)(sPb + row * 128 + SWZ(row, 8 * c4)) =
                make_ushort4(f2bf(p.x), f2bf(p.y), f2bf(p.z), f2bf(p.w));
        }
        // stage V transposed: thread owns a 4k x 4d block
        {
            float vv[4][4];
#pragma unroll
            for (int j = 0; j < 4; ++j) {
                f4 v4 = *(const f4*)(V + ((size_t)b * L_ + k0 + 4 * rsub + j) * D_ + 4 * c4);
                vv[j][0] = v4.x; vv[j][1] = v4.y; vv[j][2] = v4.z; vv[j][3] = v4.w;
            }
#pragma unroll
            for (int dj = 0; dj < 4; ++dj) {
                int rowd = 4 * c4 + dj;
                *(ushort4*)(sVb + rowd * 128 + SWZ(rowd, 8 * rsub)) =
                    make_ushort4(f2bf(vv[0][dj]), f2bf(vv[1][dj]),
                                 f2bf(vv[2][dj]), f2bf(vv[3][dj]));
            }
        }
        __syncthreads();

        bf16x8 vf[2];
#pragma unroll
        for (int kc = 0; kc < 2; ++kc)
            vf[kc] = *(const bf16x8*)(sVb + (16 * w + fr) * 128 +
                                      SWZ(16 * w + fr, kc * 64 + fc * 16));
#pragma unroll
        for (int rt = 0; rt < 4; ++rt)
#pragma unroll
            for (int kc = 0; kc < 2; ++kc) {
                bf16x8 a = *(const bf16x8*)(sPb + (rt * 16 + fr) * 128 +
                                            SWZ(rt * 16 + fr, kc * 64 + fc * 16));
                acc[rt] = MFMA16(a, vf[kc], acc[rt]);
            }
    }

#pragma unroll
    for (int rt = 0; rt < 4; ++rt)
#pragma unroll
        for (int rr = 0; rr < 4; ++rr)
            O[((size_t)b * L_ + q0 + rt * 16 + fc * 4 + rr) * D_ + 16 * w + fr] =
                acc[rt][rr];
}

// ---------------------------------------------------------------------------
extern "C" void kernel_launch(void* const* d_in, const int* in_sizes, int n_in,
                              void* d_out, int out_size, void* d_ws, size_t ws_size,
                              hipStream_t stream)
{
    const float* Q  = (const float*)d_in[0];
    const float* K  = (const float*)d_in[1];
    const float* V  = (const float*)d_in[2];
    const float* Er = (const float*)d_in[3];
    // d_in[4] (causal mask) is deterministic; computed analytically.

    float* Out  = (float*)d_out;                          // [B, L, D]
    float* Attn = (float*)d_out + (size_t)B_ * L_ * D_;   // [B, L, L] scores->probs

    k1_scores<<<B_ * NTRI, 256, 0, stream>>>(Q, K, Er, Attn);
    k2_stats<<<B_ * L_ / 4, 256, 0, stream>>>(Attn, Out);
    k3_pv<<<dim3(B_, NQT), 256, 0, stream>>>(Attn, V, Out);
}

// Round 3
// 144.918 us; speedup vs baseline: 2.5349x; 1.3421x over previous
//
#include <hip/hip_runtime.h>
#include <math.h>

#define B_ 64
#define L_ 1024
#define D_ 64
#define NQT 16

typedef float4 f4;
typedef __attribute__((ext_vector_type(8))) short bf16x8;
typedef __attribute__((ext_vector_type(4))) float f32x4;

#define MFMA16(a, b, c) __builtin_amdgcn_mfma_f32_16x16x32_bf16(a, b, c, 0, 0, 0)
#define EXP2(x) __builtin_amdgcn_exp2f(x)
#define SWZ(row, off) ((off) ^ ((((row) ^ ((row) >> 3)) & 7) << 4))
#define SRD 130                        // sR row stride (floats): 2-way scatter, <=4-way gather
#define SCL 0.18033688011112042f       // log2(e) / TEMP

__device__ __forceinline__ ushort f2bf(float x) {
    unsigned u = __float_as_uint(x);
    return (ushort)((u + 0x7FFFu + ((u >> 16) & 1u)) >> 16);
}

// One block = one (batch, 64-row q-strip). Phase A: online row stats (scores
// discarded). Phase B: recompute scores (bit-identical), write probs, PV MFMA.
__global__ __launch_bounds__(256, 2) void fused_attn(
    const float* __restrict__ Q, const float* __restrict__ Kp,
    const float* __restrict__ V, const float* __restrict__ Er,
    float* __restrict__ Pout, float* __restrict__ O)
{
    __shared__ __align__(16) char sLDS[70144];
    ushort* sQ = (ushort*)sLDS;                 // [64][72] bf16 (dead after qf load)
    ushort* sK = (ushort*)(sLDS + 9216);        // [64][72] bf16
    ushort* sE = (ushort*)(sLDS + 18432);       // [128][72] bf16
    float*  sR = (float*)(sLDS + 36864);        // [64][130] f32 skew scratch
    float*  sStat = (float*)sLDS;               // reuse sQ: wp[64][4]f2 + fs[64]f2
    char*   sPb = sLDS + 18432;                 // reuse sE: [64][128B] bf16 swz
    char*   sVb = sLDS + 18432 + 8192;          // reuse sE: [64][128B] bf16 swz

    const int tid = threadIdx.x;
    const int b  = blockIdx.x;
    const int qt = 15 - (int)blockIdx.y;        // heavy strips dispatch first
    const int q0 = qt * 64;
    const int c4 = tid & 15, rsub = tid >> 4;
    const int lane = tid & 63, w = tid >> 6;
    const int fr = lane & 15, fc = lane >> 4;
    const int l_base0 = (L_ - 64) - q0;         // Er window base minus k0

    // ---- stage Q once; fragments live in registers for both phases ----
#pragma unroll
    for (int i = 0; i < 4; ++i) {
        int row = rsub + 16 * i;
        f4 qv = *(const f4*)(Q + ((size_t)b * L_ + q0 + row) * D_ + 4 * c4);
        *(ushort4*)(sQ + row * 72 + 4 * c4) =
            make_ushort4(f2bf(qv.x), f2bf(qv.y), f2bf(qv.z), f2bf(qv.w));
    }
    __syncthreads();
    bf16x8 qf[4][2];
#pragma unroll
    for (int rt = 0; rt < 4; ++rt)
#pragma unroll
        for (int kc = 0; kc < 2; ++kc)
            qf[rt][kc] = *(const bf16x8*)(sQ + (rt * 16 + fr) * 72 + kc * 32 + fc * 8);

    float mloc[16], sloc[16];
#pragma unroll
    for (int i = 0; i < 16; ++i) { mloc[i] = -1e30f; sloc[i] = 0.0f; }

    // ================= PHASE A: online (max, sumexp) =================
    for (int kt = 0; kt <= qt; ++kt) {
        const int k0 = kt * 64;
        __syncthreads();                         // prior sK/sE/sR readers done
#pragma unroll
        for (int i = 0; i < 4; ++i) {
            int row = rsub + 16 * i;
            f4 kv = *(const f4*)(Kp + ((size_t)b * L_ + k0 + row) * D_ + 4 * c4);
            *(ushort4*)(sK + row * 72 + 4 * c4) =
                make_ushort4(f2bf(kv.x), f2bf(kv.y), f2bf(kv.z), f2bf(kv.w));
        }
#pragma unroll
        for (int i = 0; i < 8; ++i) {
            int trow = rsub + 16 * i;
            int l = l_base0 + k0 + trow;
            if (l > L_ - 1) l = L_ - 1;          // clamp: masked entries only
            f4 ev = *(const f4*)(Er + (size_t)l * D_ + 4 * c4);
            *(ushort4*)(sE + trow * 72 + 4 * c4) =
                make_ushort4(f2bf(ev.x), f2bf(ev.y), f2bf(ev.z), f2bf(ev.w));
        }
        __syncthreads();

        bf16x8 kf[2], ef[2][2];
#pragma unroll
        for (int kc = 0; kc < 2; ++kc)
            kf[kc] = *(const bf16x8*)(sK + (16 * w + fr) * 72 + kc * 32 + fc * 8);
#pragma unroll
        for (int c = 0; c < 2; ++c)
#pragma unroll
            for (int kc = 0; kc < 2; ++kc)
                ef[c][kc] = *(const bf16x8*)(sE + ((2 * w + c) * 16 + fr) * 72 + kc * 32 + fc * 8);

        f32x4 accC[4] = {};
        f32x4 accR[4][2] = {};
#pragma unroll
        for (int rt = 0; rt < 4; ++rt)
#pragma unroll
            for (int kc = 0; kc < 2; ++kc) {
                accC[rt]    = MFMA16(qf[rt][kc], kf[kc],    accC[rt]);
                accR[rt][0] = MFMA16(qf[rt][kc], ef[0][kc], accR[rt][0]);
                accR[rt][1] = MFMA16(qf[rt][kc], ef[1][kc], accR[rt][1]);
            }
#pragma unroll
        for (int rt = 0; rt < 4; ++rt)
#pragma unroll
            for (int c = 0; c < 2; ++c)
#pragma unroll
                for (int r = 0; r < 4; ++r)
                    sR[(rt * 16 + fc * 4 + r) * SRD + (2 * w + c) * 16 + fr] = accR[rt][c][r];
        __syncthreads();

        const bool diag = (kt == qt);
#pragma unroll
        for (int rt = 0; rt < 4; ++rt)
#pragma unroll
            for (int r = 0; r < 4; ++r) {
                const int qi = rt * 16 + fc * 4 + r;
                const int kj = 16 * w + fr;
                float rel = sR[qi * SRD + kj - qi + 63];
                float v = (accC[rt][r] + rel) * SCL;
                if (!(diag && kj > qi)) {
                    const int idx = rt * 4 + r;
                    float mn = fmaxf(mloc[idx], v);
                    sloc[idx] = sloc[idx] * EXP2(mloc[idx] - mn) + EXP2(v - mn);
                    mloc[idx] = mn;
                }
            }
    }

    // ---- per-row reduce: butterfly over the 16 fr-lanes, then across waves ----
#pragma unroll
    for (int off = 1; off <= 8; off <<= 1)
#pragma unroll
        for (int i = 0; i < 16; ++i) {
            float mo = __shfl_xor(mloc[i], off, 64);
            float so = __shfl_xor(sloc[i], off, 64);
            float mn = fmaxf(mloc[i], mo);
            sloc[i] = sloc[i] * EXP2(mloc[i] - mn) + so * EXP2(mo - mn);
            mloc[i] = mn;
        }
    __syncthreads();                              // last sR readers done; sQ long dead
    if (fr == 0) {
#pragma unroll
        for (int i = 0; i < 16; ++i) {
            int row = (i >> 2) * 16 + fc * 4 + (i & 3);
            ((float2*)sStat)[row * 4 + w] = make_float2(mloc[i], sloc[i]);
        }
    }
    __syncthreads();
    if (tid < 64) {
        float2 p0 = ((float2*)sStat)[tid * 4 + 0];
        float2 p1 = ((float2*)sStat)[tid * 4 + 1];
        float2 p2 = ((float2*)sStat)[tid * 4 + 2];
        float2 p3 = ((float2*)sStat)[tid * 4 + 3];
        float m = fmaxf(fmaxf(p0.x, p1.x), fmaxf(p2.x, p3.x));
        float s = p0.y * EXP2(p0.x - m) + p1.y * EXP2(p1.x - m) +
                  p2.y * EXP2(p2.x - m) + p3.y * EXP2(p3.x - m);
        ((float2*)(sStat + 512))[tid] = make_float2(m, 1.0f / s);
    }
    __syncthreads();
#pragma unroll
    for (int i = 0; i < 16; ++i) {
        int row = (i >> 2) * 16 + fc * 4 + (i & 3);
        float2 f = ((float2*)(sStat + 512))[row];
        mloc[i] = f.x;                            // row max
        sloc[i] = f.y;                            // 1/sum
    }

    f32x4 accO[4] = {};

    // ================= PHASE B: probs + PV =================
    for (int kt = 0; kt <= qt; ++kt) {
        const int k0 = kt * 64;
        __syncthreads();                          // prior PV frag reads done
        f4 vv[4];                                 // V loads early (latency hides)
#pragma unroll
        for (int j = 0; j < 4; ++j)
            vv[j] = *(const f4*)(V + ((size_t)b * L_ + k0 + 4 * rsub + j) * D_ + 4 * c4);
#pragma unroll
        for (int i = 0; i < 4; ++i) {
            int row = rsub + 16 * i;
            f4 kv = *(const f4*)(Kp + ((size_t)b * L_ + k0 + row) * D_ + 4 * c4);
            *(ushort4*)(sK + row * 72 + 4 * c4) =
                make_ushort4(f2bf(kv.x), f2bf(kv.y), f2bf(kv.z), f2bf(kv.w));
        }
#pragma unroll
        for (int i = 0; i < 8; ++i) {
            int trow = rsub + 16 * i;
            int l = l_base0 + k0 + trow;
            if (l > L_ - 1) l = L_ - 1;
            f4 ev = *(const f4*)(Er + (size_t)l * D_ + 4 * c4);
            *(ushort4*)(sE + trow * 72 + 4 * c4) =
                make_ushort4(f2bf(ev.x), f2bf(ev.y), f2bf(ev.z), f2bf(ev.w));
        }
        __syncthreads();

        bf16x8 kf[2], ef[2][2];
#pragma unroll
        for (int kc = 0; kc < 2; ++kc)
            kf[kc] = *(const bf16x8*)(sK + (16 * w + fr) * 72 + kc * 32 + fc * 8);
#pragma unroll
        for (int c = 0; c < 2; ++c)
#pragma unroll
            for (int kc = 0; kc < 2; ++kc)
                ef[c][kc] = *(const bf16x8*)(sE + ((2 * w + c) * 16 + fr) * 72 + kc * 32 + fc * 8);

        f32x4 accC[4] = {};
        f32x4 accR[4][2] = {};
#pragma unroll
        for (int rt = 0; rt < 4; ++rt)
#pragma unroll
            for (int kc = 0; kc < 2; ++kc) {
                accC[rt]    = MFMA16(qf[rt][kc], kf[kc],    accC[rt]);
                accR[rt][0] = MFMA16(qf[rt][kc], ef[0][kc], accR[rt][0]);
                accR[rt][1] = MFMA16(qf[rt][kc], ef[1][kc], accR[rt][1]);
            }
#pragma unroll
        for (int rt = 0; rt < 4; ++rt)
#pragma unroll
            for (int c = 0; c < 2; ++c)
#pragma unroll
                for (int r = 0; r < 4; ++r)
                    sR[(rt * 16 + fc * 4 + r) * SRD + (2 * w + c) * 16 + fr] = accR[rt][c][r];
        __syncthreads();                          // also: all ef reads done -> sPb/sVb safe

        const bool diag = (kt == qt);
#pragma unroll
        for (int rt = 0; rt < 4; ++rt)
#pragma unroll
            for (int r = 0; r < 4; ++r) {
                const int qi = rt * 16 + fc * 4 + r;
                const int kj = 16 * w + fr;
                float rel = sR[qi * SRD + kj - qi + 63];
                float v = (accC[rt][r] + rel) * SCL;
                const int idx = rt * 4 + r;
                float p = (diag && kj > qi) ? 0.0f : EXP2(v - mloc[idx]) * sloc[idx];
                Pout[((size_t)b * L_ + q0 + qi) * L_ + k0 + kj] = p;
                *(ushort*)(sPb + qi * 128 + SWZ(qi, 2 * kj)) = f2bf(p);
            }
        // V^T staging from the reg-held loads
#pragma unroll
        for (int dj = 0; dj < 4; ++dj) {
            int rowd = 4 * c4 + dj;
            float e0 = (&vv[0].x)[dj], e1 = (&vv[1].x)[dj],
                  e2 = (&vv[2].x)[dj], e3 = (&vv[3].x)[dj];
            *(ushort4*)(sVb + rowd * 128 + SWZ(rowd, 8 * rsub)) =
                make_ushort4(f2bf(e0), f2bf(e1), f2bf(e2), f2bf(e3));
        }
        __syncthreads();

        bf16x8 vf[2];
#pragma unroll
        for (int kc = 0; kc < 2; ++kc)
            vf[kc] = *(const bf16x8*)(sVb + (16 * w + fr) * 128 +
                                      SWZ(16 * w + fr, kc * 64 + fc * 16));
#pragma unroll
        for (int rt = 0; rt < 4; ++rt)
#pragma unroll
            for (int kc = 0; kc < 2; ++kc) {
                bf16x8 pa = *(const bf16x8*)(sPb + (rt * 16 + fr) * 128 +
                                             SWZ(rt * 16 + fr, kc * 64 + fc * 16));
                accO[rt] = MFMA16(pa, vf[kc], accO[rt]);
            }
    }

    // ---- zeros for the never-touched upper region of this strip ----
    const int nz4 = 16 * (15 - qt);
    const f4 z = {0.0f, 0.0f, 0.0f, 0.0f};
#pragma unroll
    for (int i = 0; i < 4; ++i) {
        int row = rsub + 16 * i;
        float* base = Pout + ((size_t)b * L_ + q0 + row) * L_ + 64 * (qt + 1);
        for (int c = c4; c < nz4; c += 16)
            *(f4*)(base + 4 * c) = z;
    }
    // ---- O epilogue ----
#pragma unroll
    for (int rt = 0; rt < 4; ++rt)
#pragma unroll
        for (int rr = 0; rr < 4; ++rr)
            O[((size_t)b * L_ + q0 + rt * 16 + fc * 4 + rr) * D_ + 16 * w + fr] =
                accO[rt][rr];
}

// ---------------------------------------------------------------------------
extern "C" void kernel_launch(void* const* d_in, const int* in_sizes, int n_in,
                              void* d_out, int out_size, void* d_ws, size_t ws_size,
                              hipStream_t stream)
{
    const float* Q  = (const float*)d_in[0];
    const float* K  = (const float*)d_in[1];
    const float* V  = (const float*)d_in[2];
    const float* Er = (const float*)d_in[3];
    // d_in[4] (causal mask) is deterministic; handled analytically.

    float* Out  = (float*)d_out;                          // [B, L, D]
    float* Attn = (float*)d_out + (size_t)B_ * L_ * D_;   // [B, L, L] probs

    fused_attn<<<dim3(B_, NQT), 256, 0, stream>>>(Q, K, V, Er, Attn, Out);
}